// Round 1
// baseline (379.483 us; speedup 1.0000x reference)
//
#include <hip/hip_runtime.h>
#include <hip/hip_bf16.h>

#define B_ 2
#define S_ 2048
#define D_ 1024
#define H_ 16
#define AD_ 64

typedef __attribute__((ext_vector_type(8))) short bf16x8;
typedef __attribute__((ext_vector_type(4))) float f32x4;

__device__ inline unsigned short f2bf(float f) {
  __hip_bfloat16 h = __float2bfloat16(f);
  return *reinterpret_cast<unsigned short*>(&h);
}

__device__ inline void gload16(const void* g, void* lds) {
  __builtin_amdgcn_global_load_lds((const __attribute__((address_space(1))) void*)g,
                                   (__attribute__((address_space(3))) void*)lds,
                                   16, 0, 0);
}

// ---------------------------------------------------------------------------
// Transpose + cast W (1024x1024 f32 [k][n]) -> Wt bf16 [n][k]
// ---------------------------------------------------------------------------
__global__ __launch_bounds__(256) void wtrans(const float* __restrict__ W,
                                              __hip_bfloat16* __restrict__ Wt) {
  __shared__ alignas(16) unsigned short T[64][72];  // padded stride, conflict-free-ish
  const int tx = threadIdx.x;
  const int n0 = blockIdx.x * 64, k0 = blockIdx.y * 64;
#pragma unroll
  for (int i = 0; i < 4; ++i) {
    int kl = (tx >> 4) + i * 16;
    int nl = (tx & 15) * 4;
    float4 val = *(const float4*)(W + (size_t)(k0 + kl) * 1024 + n0 + nl);
    T[kl][nl + 0] = f2bf(val.x);
    T[kl][nl + 1] = f2bf(val.y);
    T[kl][nl + 2] = f2bf(val.z);
    T[kl][nl + 3] = f2bf(val.w);
  }
  __syncthreads();
#pragma unroll
  for (int i = 0; i < 4; ++i) {
    int nl = (tx >> 4) + i * 16;
    int kl = (tx & 15) * 4;
    ushort4 o;
    o.x = T[kl + 0][nl];
    o.y = T[kl + 1][nl];
    o.z = T[kl + 2][nl];
    o.w = T[kl + 3][nl];
    *(ushort4*)(Wt + (size_t)(n0 + nl) * 1024 + k0 + kl) = o;
  }
}

// ---------------------------------------------------------------------------
// 128x128 tile GEMM, BK=32, 4 waves (2x2), MFMA 16x16x32 bf16.
//   A: (4096 x 1024), f32 (reg-staged+cast) or bf16 (global_load_lds).
//   Bt: bf16 [n][k] (pre-transposed weights) staged via global_load_lds.
// MODE 0: C -> bf16 head layout  [b,h,s,ad]
// MODE 1: C -> bf16 transposed   [b,h,ad,s]   (for V)
// MODE 2: C -> f32 plain [m][n]               (final output x)
// XOR swizzle on 16B chunks: chunk ^= (row ^ (row>>2)) & 3  (involution)
// ---------------------------------------------------------------------------
template <bool AF32, int MODE>
__global__ __launch_bounds__(256) void gemm128(const void* __restrict__ Ap,
                                               const __hip_bfloat16* __restrict__ Bt,
                                               void* __restrict__ Cp) {
  __shared__ alignas(16) __hip_bfloat16 As[128 * 32];
  __shared__ alignas(16) __hip_bfloat16 Bs[128 * 32];
  const int tid = threadIdx.x;
  const int wave = tid >> 6, lane = tid & 63;
  const int g = lane >> 4, c = lane & 15;
  const int bm = blockIdx.x * 128, bn = blockIdx.y * 128;
  const int wr = (wave >> 1) * 64, wc = (wave & 1) * 64;
  f32x4 acc[4][4] = {};

  for (int k0 = 0; k0 < D_; k0 += 32) {
    if constexpr (AF32) {
      const float* A = (const float*)Ap;
#pragma unroll
      for (int i = 0; i < 4; ++i) {
        int chunk = i * 256 + tid;  // 1024 chunks of 4 f32
        int m = chunk >> 3, kc = chunk & 7;
        float4 v = *(const float4*)(A + (size_t)(bm + m) * D_ + k0 + kc * 4);
        ushort4 b;
        b.x = f2bf(v.x); b.y = f2bf(v.y); b.z = f2bf(v.z); b.w = f2bf(v.w);
        int sw = (kc >> 1) ^ ((m ^ (m >> 2)) & 3);
        *(ushort4*)((char*)As + m * 64 + (sw << 4) + ((kc & 1) << 3)) = b;
      }
    } else {
      const __hip_bfloat16* A = (const __hip_bfloat16*)Ap;
#pragma unroll
      for (int i = 0; i < 2; ++i) {
        int cb = i * 256 + wave * 64;  // wave-uniform LDS chunk base
        int chunk = cb + lane;
        int m = chunk >> 2, kc = chunk & 3;
        int sw = kc ^ ((m ^ (m >> 2)) & 3);
        gload16(A + (size_t)(bm + m) * D_ + k0 + sw * 8, (char*)As + cb * 16);
      }
    }
#pragma unroll
    for (int i = 0; i < 2; ++i) {
      int cb = i * 256 + wave * 64;
      int chunk = cb + lane;
      int n = chunk >> 2, kc = chunk & 3;
      int sw = kc ^ ((n ^ (n >> 2)) & 3);
      gload16(Bt + (size_t)(bn + n) * D_ + k0 + sw * 8, (char*)Bs + cb * 16);
    }
    __syncthreads();

    bf16x8 a[4], b[4];
#pragma unroll
    for (int mi = 0; mi < 4; ++mi) {
      int row = wr + mi * 16 + c;
      a[mi] = *(const bf16x8*)((const char*)As + row * 64 +
                               ((g ^ ((row ^ (row >> 2)) & 3)) << 4));
    }
#pragma unroll
    for (int ni = 0; ni < 4; ++ni) {
      int row = wc + ni * 16 + c;
      b[ni] = *(const bf16x8*)((const char*)Bs + row * 64 +
                               ((g ^ ((row ^ (row >> 2)) & 3)) << 4));
    }
#pragma unroll
    for (int mi = 0; mi < 4; ++mi)
#pragma unroll
      for (int ni = 0; ni < 4; ++ni)
        acc[mi][ni] =
            __builtin_amdgcn_mfma_f32_16x16x32_bf16(a[mi], b[ni], acc[mi][ni], 0, 0, 0);
    __syncthreads();
  }

  // epilogue: C/D layout col = lane&15, row = (lane>>4)*4 + r
#pragma unroll
  for (int mi = 0; mi < 4; ++mi) {
#pragma unroll
    for (int ni = 0; ni < 4; ++ni) {
#pragma unroll
      for (int r = 0; r < 4; ++r) {
        int grow = bm + wr + mi * 16 + g * 4 + r;
        int gcol = bn + wc + ni * 16 + c;
        float val = acc[mi][ni][r];
        if constexpr (MODE == 2) {
          ((float*)Cp)[(size_t)grow * 1024 + gcol] = val;
        } else {
          int bb = grow >> 11, s = grow & 2047;
          int h = gcol >> 6, ad = gcol & 63;
          __hip_bfloat16* C = (__hip_bfloat16*)Cp;
          if constexpr (MODE == 0)
            C[(((size_t)(bb * H_ + h)) * S_ + s) * AD_ + ad] = __float2bfloat16(val);
          else
            C[(((size_t)(bb * H_ + h)) * AD_ + ad) * S_ + s] = __float2bfloat16(val);
        }
      }
    }
  }
}

// ---------------------------------------------------------------------------
// Fused attention. Block = 4 waves, 64 q-rows per block (16 per wave).
// Pass 1: rowsum of exp(logits) (no max-sub; logits bounded ~|6|).
// Pass 2: recompute logits, write attn = exp*invZ (f32), accumulate PV.
// K LDS [key][ad], V LDS [ad][key] (from pre-transposed Vt), both 64x64 bf16,
// XOR-swizzled (chunk ^= row&7) via pre-swizzled global_load_lds sources.
// ---------------------------------------------------------------------------
__global__ __launch_bounds__(256) void attn_fused(const __hip_bfloat16* __restrict__ Qh,
                                                  const __hip_bfloat16* __restrict__ Kh,
                                                  const __hip_bfloat16* __restrict__ Vt,
                                                  float* __restrict__ attn,
                                                  __hip_bfloat16* __restrict__ ctx) {
  __shared__ alignas(16) __hip_bfloat16 Ks[64 * 64];
  __shared__ alignas(16) __hip_bfloat16 Vs[64 * 64];
  __shared__ alignas(16) __hip_bfloat16 Ps[4][16 * 64];
  const int tid = threadIdx.x;
  const int wave = tid >> 6, lane = tid & 63;
  const int g = lane >> 4, c = lane & 15;
  const int qt = blockIdx.x, bh = blockIdx.y;
  const int qrow0 = qt * 64 + wave * 16;

  const __hip_bfloat16* Kbh = Kh + (size_t)bh * S_ * AD_;
  const __hip_bfloat16* Vbh = Vt + (size_t)bh * AD_ * S_;

  // Q fragments live in registers for the whole kernel (A-operand, rows = c)
  const __hip_bfloat16* Qbase = Qh + ((size_t)bh * S_ + qrow0 + c) * AD_;
  bf16x8 qa0 = *(const bf16x8*)(Qbase + g * 8);
  bf16x8 qa1 = *(const bf16x8*)(Qbase + 32 + g * 8);

  float rowsum[4] = {0.f, 0.f, 0.f, 0.f};

  // ---- pass 1: row sums ----
  for (int kt = 0; kt < 32; ++kt) {
#pragma unroll
    for (int i = 0; i < 2; ++i) {
      int cb = i * 256 + wave * 64;
      int chunk = cb + lane;
      int key = chunk >> 3, kc = chunk & 7;
      gload16(Kbh + (size_t)(kt * 64 + key) * AD_ + ((kc ^ (key & 7)) * 8),
              (char*)Ks + cb * 16);
    }
    __syncthreads();
    float part[4] = {0.f, 0.f, 0.f, 0.f};
#pragma unroll
    for (int ni = 0; ni < 4; ++ni) {
      int key = ni * 16 + c;
      const char* kb = (const char*)Ks + key * 128;
      bf16x8 b0 = *(const bf16x8*)(kb + ((g ^ (key & 7)) << 4));
      bf16x8 b1 = *(const bf16x8*)(kb + (((4 + g) ^ (key & 7)) << 4));
      f32x4 sa = {0.f, 0.f, 0.f, 0.f};
      sa = __builtin_amdgcn_mfma_f32_16x16x32_bf16(qa0, b0, sa, 0, 0, 0);
      sa = __builtin_amdgcn_mfma_f32_16x16x32_bf16(qa1, b1, sa, 0, 0, 0);
#pragma unroll
      for (int r = 0; r < 4; ++r) part[r] += __expf(sa[r] * 0.125f);
    }
#pragma unroll
    for (int r = 0; r < 4; ++r) {
      float e = part[r];
      e += __shfl_xor(e, 1);
      e += __shfl_xor(e, 2);
      e += __shfl_xor(e, 4);
      e += __shfl_xor(e, 8);
      rowsum[r] += e;
    }
    __syncthreads();
  }

  float invZ[4];
#pragma unroll
  for (int r = 0; r < 4; ++r) invZ[r] = 1.0f / rowsum[r];

  f32x4 ctxacc[4] = {};
  float* attn_base = attn + ((size_t)bh * S_ + qrow0) * S_;

  // ---- pass 2: attn write + PV ----
  for (int kt = 0; kt < 32; ++kt) {
#pragma unroll
    for (int i = 0; i < 2; ++i) {
      int cb = i * 256 + wave * 64;
      int chunk = cb + lane;
      int key = chunk >> 3, kc = chunk & 7;
      gload16(Kbh + (size_t)(kt * 64 + key) * AD_ + ((kc ^ (key & 7)) * 8),
              (char*)Ks + cb * 16);
    }
#pragma unroll
    for (int i = 0; i < 2; ++i) {
      int cb = i * 256 + wave * 64;
      int chunk = cb + lane;
      int ad = chunk >> 3, kc = chunk & 7;
      gload16(Vbh + (size_t)ad * S_ + kt * 64 + ((kc ^ (ad & 7)) * 8),
              (char*)Vs + cb * 16);
    }
    __syncthreads();

#pragma unroll
    for (int ni = 0; ni < 4; ++ni) {
      int key = ni * 16 + c;
      const char* kb = (const char*)Ks + key * 128;
      bf16x8 b0 = *(const bf16x8*)(kb + ((g ^ (key & 7)) << 4));
      bf16x8 b1 = *(const bf16x8*)(kb + (((4 + g) ^ (key & 7)) << 4));
      f32x4 sa = {0.f, 0.f, 0.f, 0.f};
      sa = __builtin_amdgcn_mfma_f32_16x16x32_bf16(qa0, b0, sa, 0, 0, 0);
      sa = __builtin_amdgcn_mfma_f32_16x16x32_bf16(qa1, b1, sa, 0, 0, 0);
#pragma unroll
      for (int r = 0; r < 4; ++r) {
        float p = __expf(sa[r] * 0.125f) * invZ[r];
        attn_base[(size_t)(g * 4 + r) * S_ + kt * 64 + key] = p;
        int row = g * 4 + r, col = key;
        int chk = (col >> 3) ^ (row & 7);
        *(unsigned short*)((char*)Ps[wave] + row * 128 + (chk << 4) + (col & 7) * 2) =
            f2bf(p);
      }
    }
    // PV: A = P (wave-private LDS), B = V (LDS [ad][key])
#pragma unroll
    for (int kc2 = 0; kc2 < 2; ++kc2) {
      bf16x8 pa = *(const bf16x8*)((const char*)Ps[wave] + c * 128 +
                                   ((((kc2 << 2) + g) ^ (c & 7)) << 4));
#pragma unroll
      for (int ni = 0; ni < 4; ++ni) {
        int ad = ni * 16 + c;
        bf16x8 vb = *(const bf16x8*)((const char*)Vs + ad * 128 +
                                     ((((kc2 << 2) + g) ^ (ad & 7)) << 4));
        ctxacc[ni] = __builtin_amdgcn_mfma_f32_16x16x32_bf16(pa, vb, ctxacc[ni], 0, 0, 0);
      }
    }
    __syncthreads();
  }

  // ctx write: merged head layout [b, s, h*64+ad], bf16 for final GEMM
  const int b = bh >> 4, h = bh & 15;
#pragma unroll
  for (int ni = 0; ni < 4; ++ni) {
#pragma unroll
    for (int r = 0; r < 4; ++r) {
      int qg = qrow0 + g * 4 + r;
      int col = h * 64 + ni * 16 + c;
      ctx[((size_t)b * S_ + qg) * 1024 + col] = __float2bfloat16(ctxacc[ni][r]);
    }
  }
}

// ---------------------------------------------------------------------------
extern "C" void kernel_launch(void* const* d_in, const int* in_sizes, int n_in,
                              void* d_out, int out_size, void* d_ws, size_t ws_size,
                              hipStream_t stream) {
  const float* q = (const float*)d_in[0];
  const float* k = (const float*)d_in[1];
  const float* v = (const float*)d_in[2];
  const float* WQ = (const float*)d_in[3];
  const float* WK = (const float*)d_in[4];
  const float* WV = (const float*)d_in[5];
  const float* WO = (const float*)d_in[6];

  float* out_x = (float*)d_out;                          // (B,S,1024) f32
  float* out_attn = out_x + (size_t)B_ * S_ * 1024;      // (B,H,S,S)  f32

  // workspace layout (40 MB total)
  __hip_bfloat16* WtQ = (__hip_bfloat16*)d_ws;
  __hip_bfloat16* WtK = WtQ + (size_t)1024 * 1024;
  __hip_bfloat16* WtV = WtK + (size_t)1024 * 1024;
  __hip_bfloat16* WtO = WtV + (size_t)1024 * 1024;
  __hip_bfloat16* Qh = WtO + (size_t)1024 * 1024;                 // [b,h,s,ad]
  __hip_bfloat16* Kh = Qh + (size_t)B_ * H_ * S_ * AD_;           // [b,h,s,ad]
  __hip_bfloat16* Vt = Kh + (size_t)B_ * H_ * S_ * AD_;           // [b,h,ad,s]
  __hip_bfloat16* ctx = Vt + (size_t)B_ * H_ * S_ * AD_;          // [b,s,1024]

  dim3 tgrid(16, 16);
  wtrans<<<tgrid, 256, 0, stream>>>(WQ, WtQ);
  wtrans<<<tgrid, 256, 0, stream>>>(WK, WtK);
  wtrans<<<tgrid, 256, 0, stream>>>(WV, WtV);
  wtrans<<<tgrid, 256, 0, stream>>>(WO, WtO);

  dim3 ggrid(32, 8);  // M=4096/128, N=1024/128
  gemm128<true, 0><<<ggrid, 256, 0, stream>>>(q, WtQ, Qh);
  gemm128<true, 0><<<ggrid, 256, 0, stream>>>(k, WtK, Kh);
  gemm128<true, 1><<<ggrid, 256, 0, stream>>>(v, WtV, Vt);

  attn_fused<<<dim3(32, 32), 256, 0, stream>>>(Qh, Kh, Vt, out_attn, ctx);

  gemm128<false, 2><<<ggrid, 256, 0, stream>>>(ctx, WtO, out_x);
}